// Round 1
// baseline (1996.537 us; speedup 1.0000x reference)
//
#include <hip/hip_runtime.h>
#include <math.h>

typedef __bf16 bf16;
typedef __bf16 bf16x8 __attribute__((ext_vector_type(8)));
typedef __bf16 bf16x4 __attribute__((ext_vector_type(4)));
typedef float  f32x4  __attribute__((ext_vector_type(4)));

#define MFMA(a,b,c) __builtin_amdgcn_mfma_f32_16x16x32_bf16(a,b,c,0,0,0)

__device__ __forceinline__ float gelu_exact(float z){
    return 0.5f * z * (1.0f + erff(z * 0.70710678118654752f));
}

// ---------------- weight prep: fp32 [K,N] -> bf16 [N,K] --------------------
__global__ void wprep(const float* __restrict__ W, bf16* __restrict__ WT, int K, int N)
{
    __shared__ float tile[32][33];
    int tx = threadIdx.x, ty = threadIdx.y;
    int n0 = blockIdx.x * 32, k0 = blockIdx.y * 32;
    for (int j = 0; j < 4; j++)
        tile[ty + j*8][tx] = W[(size_t)(k0 + ty + j*8) * N + n0 + tx];
    __syncthreads();
    for (int j = 0; j < 4; j++)
        WT[(size_t)(n0 + ty + j*8) * K + k0 + tx] = (bf16)tile[tx][ty + j*8];
}

// ---------------- LayerNorm (+ optional window-partition permute) ----------
// PERM=1: out row rw (window layout) <- LN(x[orig(rw)])
template<int PERM>
__global__ __launch_bounds__(256) void ln_kernel(const float* __restrict__ x,
    const float* __restrict__ g, const float* __restrict__ beta,
    bf16* __restrict__ out)
{
    int rw = blockIdx.x;
    int src = rw;
    if (PERM){
        int w = rw >> 8, p = rw & 255;
        int b = w >> 4, inh = (w >> 2) & 3, inw = w & 3, pi = p >> 4, pj = p & 15;
        src = b * 4096 + (inh*16 + pi) * 64 + inw*16 + pj;
    }
    const float* xr = x + (size_t)src * 1024;
    int t = threadIdx.x;
    float4 xv = ((const float4*)xr)[t];
    float s  = xv.x + xv.y + xv.z + xv.w;
    float sq = xv.x*xv.x + xv.y*xv.y + xv.z*xv.z + xv.w*xv.w;
    for (int m = 1; m < 64; m <<= 1){ s += __shfl_xor(s, m); sq += __shfl_xor(sq, m); }
    __shared__ float red[8];
    int wid = t >> 6, lane = t & 63;
    if (lane == 0){ red[wid] = s; red[4 + wid] = sq; }
    __syncthreads();
    float S  = red[0] + red[1] + red[2] + red[3];
    float SQ = red[4] + red[5] + red[6] + red[7];
    float mean = S * (1.f/1024.f);
    float var  = SQ * (1.f/1024.f) - mean*mean;     // jnp.var: biased
    float rstd = rsqrtf(var + 1e-5f);
    float4 gv = ((const float4*)g)[t];
    float4 bv = ((const float4*)beta)[t];
    bf16x4 o;
    o[0] = (bf16)((xv.x - mean) * rstd * gv.x + bv.x);
    o[1] = (bf16)((xv.y - mean) * rstd * gv.y + bv.y);
    o[2] = (bf16)((xv.z - mean) * rstd * gv.z + bv.z);
    o[3] = (bf16)((xv.w - mean) * rstd * gv.w + bv.w);
    *(bf16x4*)(out + (size_t)rw * 1024 + t*4) = o;
}

// ---------------- generic 128x128 bf16 GEMM ------------------------------
// C[M,N] = epi(A[M,K] @ BT[N,K]^T + bias)
// EPI 0: bf16 out, +bias            (QKV)
// EPI 1: bf16 out, +bias, GELU      (MLP1)
// EPI 2: f32 out, +bias, +res, un-permute rows (O-proj -> x2)
// EPI 3: f32 out, +bias, +res       (MLP2 -> d_out)
template<int EPI>
__global__ __launch_bounds__(256) void gemm128(
    const bf16* __restrict__ A, const bf16* __restrict__ BT,
    const float* __restrict__ bias, const float* __restrict__ res,
    void* __restrict__ outp, int M, int N, int K)
{
    __shared__ bf16 As[128 * 40];   // stride 40 (80B: 16B-aligned, 2-way banks)
    __shared__ bf16 Bs[128 * 40];
    int m0 = blockIdx.y * 128, n0 = blockIdx.x * 128;
    int t = threadIdx.x;
    int lane = t & 63, wid = t >> 6;
    int wm = wid >> 1, wn = wid & 1;
    int qoff = lane & 15, quad = lane >> 4;
    f32x4 acc[4][4] = {};

    for (int k0 = 0; k0 < K; k0 += 32){
        for (int i = 0; i < 2; i++){
            int idx = t + i*256;
            int row = idx >> 2, c4 = idx & 3;
            *(bf16x8*)&As[row*40 + c4*8] =
                *(const bf16x8*)&A[(size_t)(m0 + row) * K + k0 + c4*8];
            *(bf16x8*)&Bs[row*40 + c4*8] =
                *(const bf16x8*)&BT[(size_t)(n0 + row) * K + k0 + c4*8];
        }
        __syncthreads();
        bf16x8 af[4], bfr[4];
        for (int mt = 0; mt < 4; mt++)
            af[mt]  = *(bf16x8*)&As[(wm*64 + mt*16 + qoff)*40 + quad*8];
        for (int nt = 0; nt < 4; nt++)
            bfr[nt] = *(bf16x8*)&Bs[(wn*64 + nt*16 + qoff)*40 + quad*8];
        for (int mt = 0; mt < 4; mt++)
            for (int nt = 0; nt < 4; nt++)
                acc[mt][nt] = MFMA(af[mt], bfr[nt], acc[mt][nt]);
        __syncthreads();
    }

    // epilogue: C/D layout col=lane&15, row=quad*4+reg  [m91-verified]
    for (int mt = 0; mt < 4; mt++){
        for (int reg = 0; reg < 4; reg++){
            int grow = m0 + wm*64 + mt*16 + quad*4 + reg;
            size_t orow = (size_t)grow;
            if (EPI == 2){
                int w = grow >> 8, p = grow & 255;
                int b = w >> 4, inh = (w >> 2) & 3, inw = w & 3, pi = p >> 4, pj = p & 15;
                orow = (size_t)b * 4096 + (inh*16 + pi) * 64 + inw*16 + pj;
            }
            for (int nt = 0; nt < 4; nt++){
                int gcol = n0 + wn*64 + nt*16 + qoff;
                float vv = acc[mt][nt][reg] + bias[gcol];
                if (EPI == 1) vv = gelu_exact(vv);
                if (EPI >= 2) vv += res[orow * (size_t)N + gcol];
                if (EPI <= 1) ((bf16*)outp)[orow * (size_t)N + gcol] = (bf16)vv;
                else          ((float*)outp)[orow * (size_t)N + gcol] = vv;
            }
        }
    }
}

// ---------------- windowed attention: 1 block per (window, head) -----------
// q/k/v layout: [32768 rows = win*256+pos][1024 cols = head*64+d] bf16
__global__ __launch_bounds__(256) void attn_kernel(
    const bf16* __restrict__ q, const bf16* __restrict__ k,
    const bf16* __restrict__ v, bf16* __restrict__ ao)
{
    __shared__ bf16 VT[64 * 264];      // V^T: [d][kk], stride 264 (16B-aligned)
    __shared__ bf16 Pw[4][16 * 136];   // per-wave P scratch, stride 136
    int wh = blockIdx.x;
    int win = wh >> 4, head = wh & 15;
    size_t base = (size_t)win * 256;
    int cb = head * 64;
    int t = threadIdx.x, lane = t & 63, wv = t >> 6;
    int qoff = lane & 15, quad = lane >> 4;

    // stage V transposed
    for (int i = 0; i < 8; i++){
        int c = t + i*256;
        int row = c >> 3, d0 = (c & 7) * 8;
        bf16x8 vvec = *(const bf16x8*)&v[(base + row) * 1024 + cb + d0];
        for (int j = 0; j < 8; j++) VT[(d0 + j) * 264 + row] = vvec[j];
    }
    __syncthreads();

    const bf16* qb = q + base * 1024 + cb;
    const bf16* kb = k + base * 1024 + cb;

    for (int qblk = 0; qblk < 4; qblk++){
        int m0 = wv * 64 + qblk * 16;
        bf16x8 aq0 = *(const bf16x8*)&qb[(size_t)(m0 + qoff) * 1024 + quad*8];
        bf16x8 aq1 = *(const bf16x8*)&qb[(size_t)(m0 + qoff) * 1024 + 32 + quad*8];
        f32x4 S[16];
        for (int nt = 0; nt < 16; nt++){
            bf16x8 b0 = *(const bf16x8*)&kb[(size_t)(nt*16 + qoff) * 1024 + quad*8];
            bf16x8 b1 = *(const bf16x8*)&kb[(size_t)(nt*16 + qoff) * 1024 + 32 + quad*8];
            f32x4 a = {0.f, 0.f, 0.f, 0.f};
            a = MFMA(aq0, b0, a);
            a = MFMA(aq1, b1, a);
            S[nt] = a;
        }
        // softmax over 256 keys; row = quad*4+reg, cols nt*16+qoff across 16 lanes
        float inv[4];
        for (int r = 0; r < 4; r++){
            float mx = -1e30f;
            for (int nt = 0; nt < 16; nt++) mx = fmaxf(mx, S[nt][r]);
            for (int m = 1; m < 16; m <<= 1) mx = fmaxf(mx, __shfl_xor(mx, m));
            float sum = 0.f;
            for (int nt = 0; nt < 16; nt++){
                float p = __expf((S[nt][r] - mx) * 0.125f);  // SCALE = 1/8
                S[nt][r] = p; sum += p;
            }
            for (int m = 1; m < 16; m <<= 1) sum += __shfl_xor(sum, m);
            inv[r] = 1.f / sum;
        }
        // PV in two k-halves through per-wave LDS (C-layout -> A-layout)
        f32x4 O[4] = {};
        for (int h = 0; h < 2; h++){
            for (int nt = 0; nt < 8; nt++)
                for (int r = 0; r < 4; r++)
                    Pw[wv][(quad*4 + r)*136 + nt*16 + qoff] = (bf16)S[h*8 + nt][r];
            for (int ks = 0; ks < 4; ks++){
                bf16x8 ap = *(bf16x8*)&Pw[wv][qoff*136 + ks*32 + quad*8];
                for (int vt = 0; vt < 4; vt++){
                    bf16x8 bvv = *(bf16x8*)&VT[(vt*16 + qoff)*264 + (h*4 + ks)*32 + quad*8];
                    O[vt] = MFMA(ap, bvv, O[vt]);
                }
            }
        }
        for (int vt = 0; vt < 4; vt++)
            for (int r = 0; r < 4; r++){
                size_t row = base + m0 + quad*4 + r;
                ao[row * 1024 + cb + vt*16 + qoff] = (bf16)(O[vt][r] * inv[r]);
            }
    }
}

// ---------------- orchestration -------------------------------------------
extern "C" void kernel_launch(void* const* d_in, const int* in_sizes, int n_in,
                              void* d_out, int out_size, void* d_ws, size_t ws_size,
                              hipStream_t stream)
{
    const float* x     = (const float*)d_in[0];
    const float* g1    = (const float*)d_in[1];
    const float* beta1 = (const float*)d_in[2];
    const float* Wq    = (const float*)d_in[3];
    const float* bq    = (const float*)d_in[4];
    const float* Wk    = (const float*)d_in[5];
    const float* bk    = (const float*)d_in[6];
    const float* Wv    = (const float*)d_in[7];
    const float* bv    = (const float*)d_in[8];
    const float* Wo    = (const float*)d_in[9];
    const float* bo    = (const float*)d_in[10];
    const float* g2    = (const float*)d_in[11];
    const float* beta2 = (const float*)d_in[12];
    const float* W1    = (const float*)d_in[13];
    const float* b1m   = (const float*)d_in[14];
    const float* W2    = (const float*)d_in[15];
    const float* b2m   = (const float*)d_in[16];

    char* ws = (char*)d_ws;
    const size_t MB = 1024ull * 1024ull;
    bf16* WqT = (bf16*)(ws + 0*MB);     // 2 MB
    bf16* WkT = (bf16*)(ws + 2*MB);     // 2 MB
    bf16* WvT = (bf16*)(ws + 4*MB);     // 2 MB
    bf16* WoT = (bf16*)(ws + 6*MB);     // 2 MB
    bf16* W1T = (bf16*)(ws + 8*MB);     // 8 MB
    bf16* W2T = (bf16*)(ws + 16*MB);    // 8 MB
    bf16* hw  = (bf16*)(ws + 24*MB);    // 64 MB  (window-layout LN1 out)
    bf16* qbf = (bf16*)(ws + 88*MB);    // 64 MB
    bf16* kbf = (bf16*)(ws + 152*MB);   // 64 MB
    bf16* vbf = (bf16*)(ws + 216*MB);   // 64 MB
    bf16* ao  = (bf16*)(ws + 24*MB);    // reuse hw (hw consumed by QKV gemms)
    bf16* m1  = (bf16*)(ws + 24*MB);    // 256 MB, overlays hw/q/k/v (all consumed)
    float* x2 = (float*)(ws + 280*MB);  // 128 MB
    bf16* h2  = (bf16*)(ws + 408*MB);   // 64 MB    -> total 472 MB

    const int M = 32768;
    dim3 tb(32, 8);

    // weight prep
    wprep<<<dim3(32, 32),  tb, 0, stream>>>(Wq, WqT, 1024, 1024);
    wprep<<<dim3(32, 32),  tb, 0, stream>>>(Wk, WkT, 1024, 1024);
    wprep<<<dim3(32, 32),  tb, 0, stream>>>(Wv, WvT, 1024, 1024);
    wprep<<<dim3(32, 32),  tb, 0, stream>>>(Wo, WoT, 1024, 1024);
    wprep<<<dim3(128, 32), tb, 0, stream>>>(W1, W1T, 1024, 4096);
    wprep<<<dim3(32, 128), tb, 0, stream>>>(W2, W2T, 4096, 1024);

    // LN1 + window partition
    ln_kernel<1><<<M, 256, 0, stream>>>(x, g1, beta1, hw);

    // QKV projections
    gemm128<0><<<dim3(8, 256), 256, 0, stream>>>(hw, WqT, bq, nullptr, qbf, M, 1024, 1024);
    gemm128<0><<<dim3(8, 256), 256, 0, stream>>>(hw, WkT, bk, nullptr, kbf, M, 1024, 1024);
    gemm128<0><<<dim3(8, 256), 256, 0, stream>>>(hw, WvT, bv, nullptr, vbf, M, 1024, 1024);

    // windowed attention (128 windows x 16 heads)
    attn_kernel<<<2048, 256, 0, stream>>>(qbf, kbf, vbf, ao);

    // O projection + bias + residual + window un-partition -> x2 (fp32)
    gemm128<2><<<dim3(8, 256), 256, 0, stream>>>(ao, WoT, bo, x, x2, M, 1024, 1024);

    // LN2
    ln_kernel<0><<<M, 256, 0, stream>>>(x2, g2, beta2, h2);

    // MLP
    gemm128<1><<<dim3(32, 256), 256, 0, stream>>>(h2, W1T, b1m, nullptr, m1, M, 4096, 1024);
    gemm128<3><<<dim3(8, 256), 256, 0, stream>>>(m1, W2T, b2m, x2, (float*)d_out, M, 1024, 4096);
}

// Round 2
// 1944.659 us; speedup vs baseline: 1.0267x; 1.0267x over previous
//
#include <hip/hip_runtime.h>
#include <math.h>
#include <stdint.h>

typedef __bf16 bf16;
typedef __bf16 bf16x8 __attribute__((ext_vector_type(8)));
typedef __bf16 bf16x4 __attribute__((ext_vector_type(4)));
typedef float  f32x4  __attribute__((ext_vector_type(4)));

#define MFMA(a,b,c) __builtin_amdgcn_mfma_f32_16x16x32_bf16(a,b,c,0,0,0)

__device__ __forceinline__ float gelu_exact(float z){
    return 0.5f * z * (1.0f + erff(z * 0.70710678118654752f));
}

// async global->LDS, 16B per lane; LDS dest = wave-uniform base + lane*16
__device__ __forceinline__ void gload16(const void* g, void* l){
    __builtin_amdgcn_global_load_lds(
        (const __attribute__((address_space(1))) uint32_t*)(uintptr_t)g,
        (__attribute__((address_space(3))) uint32_t*)(uintptr_t)l,
        16, 0, 0);
}

// ---------------- weight prep: fp32 [K,N] -> bf16 [N,K] --------------------
__global__ void wprep(const float* __restrict__ W, bf16* __restrict__ WT, int K, int N)
{
    __shared__ float tile[32][33];
    int tx = threadIdx.x, ty = threadIdx.y;
    int n0 = blockIdx.x * 32, k0 = blockIdx.y * 32;
    for (int j = 0; j < 4; j++)
        tile[ty + j*8][tx] = W[(size_t)(k0 + ty + j*8) * N + n0 + tx];
    __syncthreads();
    for (int j = 0; j < 4; j++)
        WT[(size_t)(n0 + ty + j*8) * K + k0 + tx] = (bf16)tile[tx][ty + j*8];
}

// ---------------- LayerNorm (+ optional window-partition permute) ----------
template<int PERM>
__global__ __launch_bounds__(256) void ln_kernel(const float* __restrict__ x,
    const float* __restrict__ g, const float* __restrict__ beta,
    bf16* __restrict__ out)
{
    int rw = blockIdx.x;
    int src = rw;
    if (PERM){
        int w = rw >> 8, p = rw & 255;
        int b = w >> 4, inh = (w >> 2) & 3, inw = w & 3, pi = p >> 4, pj = p & 15;
        src = b * 4096 + (inh*16 + pi) * 64 + inw*16 + pj;
    }
    const float* xr = x + (size_t)src * 1024;
    int t = threadIdx.x;
    float4 xv = ((const float4*)xr)[t];
    float s  = xv.x + xv.y + xv.z + xv.w;
    float sq = xv.x*xv.x + xv.y*xv.y + xv.z*xv.z + xv.w*xv.w;
    for (int m = 1; m < 64; m <<= 1){ s += __shfl_xor(s, m); sq += __shfl_xor(sq, m); }
    __shared__ float red[8];
    int wid = t >> 6, lane = t & 63;
    if (lane == 0){ red[wid] = s; red[4 + wid] = sq; }
    __syncthreads();
    float S  = red[0] + red[1] + red[2] + red[3];
    float SQ = red[4] + red[5] + red[6] + red[7];
    float mean = S * (1.f/1024.f);
    float var  = SQ * (1.f/1024.f) - mean*mean;     // jnp.var: biased
    float rstd = rsqrtf(var + 1e-5f);
    float4 gv = ((const float4*)g)[t];
    float4 bv = ((const float4*)beta)[t];
    bf16x4 o;
    o[0] = (bf16)((xv.x - mean) * rstd * gv.x + bv.x);
    o[1] = (bf16)((xv.y - mean) * rstd * gv.y + bv.y);
    o[2] = (bf16)((xv.z - mean) * rstd * gv.z + bv.z);
    o[3] = (bf16)((xv.w - mean) * rstd * gv.w + bv.w);
    *(bf16x4*)(out + (size_t)rw * 1024 + t*4) = o;
}

// ---------------- generic 128x128 bf16 GEMM (global_load_lds staging) ------
// C[M,N] = epi(A[M,K] @ BT[N,K]^T + bias)
// EPI 0: bf16 out, +bias            (QKV)
// EPI 1: bf16 out, +bias, GELU      (MLP1)
// EPI 2: f32 out, +bias, +res, un-permute rows (O-proj -> x2)
// EPI 3: f32 out, +bias, +res       (MLP2 -> d_out)
template<int EPI>
__global__ __launch_bounds__(256) void gemm128(
    const bf16* __restrict__ A, const bf16* __restrict__ BT,
    const float* __restrict__ bias, const float* __restrict__ res,
    void* __restrict__ outp, int M, int N, int K)
{
    __shared__ bf16 As[128 * 32];   // UNPADDED: global_load_lds dest is lane-linear
    __shared__ bf16 Bs[128 * 32];
    int m0 = blockIdx.y * 128, n0 = blockIdx.x * 128;
    int t = threadIdx.x;
    int lane = t & 63, wid = t >> 6;
    int wm = wid >> 1, wn = wid & 1;
    int qoff = lane & 15, quad = lane >> 4;
    f32x4 acc[4][4] = {};

    // staging geometry: chunk = 16B = 8 bf16 = quarter of a 32-elem row
    // chunk index (per lane) = i*256 + t ; row = chunk>>2, c4 = chunk&3
    // LDS base per (wave,i) = (i*256 + wid*64) chunks   [wave-uniform]
    for (int k0 = 0; k0 < K; k0 += 32){
        for (int i = 0; i < 2; i++){
            int chunk = i*256 + t;
            int row = chunk >> 2, c4 = chunk & 3;
            const bf16* ga = &A [(size_t)(m0 + row) * K + k0 + c4*8];
            const bf16* gb = &BT[(size_t)(n0 + row) * K + k0 + c4*8];
            bf16* la = &As[(i*256 + wid*64) * 8];
            bf16* lb = &Bs[(i*256 + wid*64) * 8];
            gload16(ga, la);
            gload16(gb, lb);
        }
        __syncthreads();   // compiler drains vmcnt before barrier
        bf16x8 af[4], bfr[4];
        for (int mt = 0; mt < 4; mt++)
            af[mt]  = *(bf16x8*)&As[(wm*64 + mt*16 + qoff)*32 + quad*8];
        for (int nt = 0; nt < 4; nt++)
            bfr[nt] = *(bf16x8*)&Bs[(wn*64 + nt*16 + qoff)*32 + quad*8];
        for (int mt = 0; mt < 4; mt++)
            for (int nt = 0; nt < 4; nt++)
                acc[mt][nt] = MFMA(af[mt], bfr[nt], acc[mt][nt]);
        __syncthreads();
    }

    // epilogue: C/D layout col=lane&15, row=quad*4+reg  [m91-verified]
    for (int mt = 0; mt < 4; mt++){
        for (int reg = 0; reg < 4; reg++){
            int grow = m0 + wm*64 + mt*16 + quad*4 + reg;
            size_t orow = (size_t)grow;
            if (EPI == 2){
                int w = grow >> 8, p = grow & 255;
                int b = w >> 4, inh = (w >> 2) & 3, inw = w & 3, pi = p >> 4, pj = p & 15;
                orow = (size_t)b * 4096 + (inh*16 + pi) * 64 + inw*16 + pj;
            }
            for (int nt = 0; nt < 4; nt++){
                int gcol = n0 + wn*64 + nt*16 + qoff;
                float vv = acc[mt][nt][reg] + bias[gcol];
                if (EPI == 1) vv = gelu_exact(vv);
                if (EPI >= 2) vv += res[orow * (size_t)N + gcol];
                if (EPI <= 1) ((bf16*)outp)[orow * (size_t)N + gcol] = (bf16)vv;
                else          ((float*)outp)[orow * (size_t)N + gcol] = vv;
            }
        }
    }
}

// ---------------- windowed attention: 1 block per (window, head) -----------
// q/k/v layout: [32768 rows = win*256+pos][1024 cols = head*64+d] bf16
__global__ __launch_bounds__(256) void attn_kernel(
    const bf16* __restrict__ q, const bf16* __restrict__ k,
    const bf16* __restrict__ v, bf16* __restrict__ ao)
{
    __shared__ bf16 VT[64 * 264];      // V^T: [d][kk], stride 264 (16B-aligned)
    __shared__ bf16 Pw[4][16 * 136];   // per-wave P scratch, stride 136
    int wh = blockIdx.x;
    int win = wh >> 4, head = wh & 15;
    size_t base = (size_t)win * 256;
    int cb = head * 64;
    int t = threadIdx.x, lane = t & 63, wv = t >> 6;
    int qoff = lane & 15, quad = lane >> 4;

    // stage V transposed
    for (int i = 0; i < 8; i++){
        int c = t + i*256;
        int row = c >> 3, d0 = (c & 7) * 8;
        bf16x8 vvec = *(const bf16x8*)&v[(base + row) * 1024 + cb + d0];
        for (int j = 0; j < 8; j++) VT[(d0 + j) * 264 + row] = vvec[j];
    }
    __syncthreads();

    const bf16* qb = q + base * 1024 + cb;
    const bf16* kb = k + base * 1024 + cb;

    for (int qblk = 0; qblk < 4; qblk++){
        int m0 = wv * 64 + qblk * 16;
        bf16x8 aq0 = *(const bf16x8*)&qb[(size_t)(m0 + qoff) * 1024 + quad*8];
        bf16x8 aq1 = *(const bf16x8*)&qb[(size_t)(m0 + qoff) * 1024 + 32 + quad*8];
        f32x4 S[16];
        for (int nt = 0; nt < 16; nt++){
            bf16x8 b0 = *(const bf16x8*)&kb[(size_t)(nt*16 + qoff) * 1024 + quad*8];
            bf16x8 b1 = *(const bf16x8*)&kb[(size_t)(nt*16 + qoff) * 1024 + 32 + quad*8];
            f32x4 a = {0.f, 0.f, 0.f, 0.f};
            a = MFMA(aq0, b0, a);
            a = MFMA(aq1, b1, a);
            S[nt] = a;
        }
        // softmax over 256 keys; row = quad*4+reg, cols nt*16+qoff across 16 lanes
        float inv[4];
        for (int r = 0; r < 4; r++){
            float mx = -1e30f;
            for (int nt = 0; nt < 16; nt++) mx = fmaxf(mx, S[nt][r]);
            for (int m = 1; m < 16; m <<= 1) mx = fmaxf(mx, __shfl_xor(mx, m));
            float sum = 0.f;
            for (int nt = 0; nt < 16; nt++){
                float p = __expf((S[nt][r] - mx) * 0.125f);  // SCALE = 1/8
                S[nt][r] = p; sum += p;
            }
            for (int m = 1; m < 16; m <<= 1) sum += __shfl_xor(sum, m);
            inv[r] = 1.f / sum;
        }
        // PV in two k-halves through per-wave LDS (C-layout -> A-layout)
        f32x4 O[4] = {};
        for (int h = 0; h < 2; h++){
            for (int nt = 0; nt < 8; nt++)
                for (int r = 0; r < 4; r++)
                    Pw[wv][(quad*4 + r)*136 + nt*16 + qoff] = (bf16)S[h*8 + nt][r];
            for (int ks = 0; ks < 4; ks++){
                bf16x8 ap = *(bf16x8*)&Pw[wv][qoff*136 + ks*32 + quad*8];
                for (int vt = 0; vt < 4; vt++){
                    bf16x8 bvv = *(bf16x8*)&VT[(vt*16 + qoff)*264 + (h*4 + ks)*32 + quad*8];
                    O[vt] = MFMA(ap, bvv, O[vt]);
                }
            }
        }
        for (int vt = 0; vt < 4; vt++)
            for (int r = 0; r < 4; r++){
                size_t row = base + m0 + quad*4 + r;
                ao[row * 1024 + cb + vt*16 + qoff] = (bf16)(O[vt][r] * inv[r]);
            }
    }
}

// ---------------- orchestration -------------------------------------------
extern "C" void kernel_launch(void* const* d_in, const int* in_sizes, int n_in,
                              void* d_out, int out_size, void* d_ws, size_t ws_size,
                              hipStream_t stream)
{
    const float* x     = (const float*)d_in[0];
    const float* g1    = (const float*)d_in[1];
    const float* beta1 = (const float*)d_in[2];
    const float* Wq    = (const float*)d_in[3];
    const float* bq    = (const float*)d_in[4];
    const float* Wk    = (const float*)d_in[5];
    const float* bk    = (const float*)d_in[6];
    const float* Wv    = (const float*)d_in[7];
    const float* bv    = (const float*)d_in[8];
    const float* Wo    = (const float*)d_in[9];
    const float* bo    = (const float*)d_in[10];
    const float* g2    = (const float*)d_in[11];
    const float* beta2 = (const float*)d_in[12];
    const float* W1    = (const float*)d_in[13];
    const float* b1m   = (const float*)d_in[14];
    const float* W2    = (const float*)d_in[15];
    const float* b2m   = (const float*)d_in[16];

    char* ws = (char*)d_ws;
    const size_t MB = 1024ull * 1024ull;
    bf16* WqT = (bf16*)(ws + 0*MB);     // 2 MB
    bf16* WkT = (bf16*)(ws + 2*MB);     // 2 MB
    bf16* WvT = (bf16*)(ws + 4*MB);     // 2 MB
    bf16* WoT = (bf16*)(ws + 6*MB);     // 2 MB
    bf16* W1T = (bf16*)(ws + 8*MB);     // 8 MB
    bf16* W2T = (bf16*)(ws + 16*MB);    // 8 MB
    bf16* hw  = (bf16*)(ws + 24*MB);    // 64 MB  (window-layout LN1 out)
    bf16* qbf = (bf16*)(ws + 88*MB);    // 64 MB
    bf16* kbf = (bf16*)(ws + 152*MB);   // 64 MB
    bf16* vbf = (bf16*)(ws + 216*MB);   // 64 MB
    bf16* ao  = (bf16*)(ws + 24*MB);    // reuse hw (hw consumed by QKV gemms)
    bf16* m1  = (bf16*)(ws + 24*MB);    // 256 MB, overlays hw/q/k/v (all consumed)
    float* x2 = (float*)(ws + 280*MB);  // 128 MB
    bf16* h2  = (bf16*)(ws + 408*MB);   // 64 MB    -> total 472 MB

    const int M = 32768;
    dim3 tb(32, 8);

    // weight prep
    wprep<<<dim3(32, 32),  tb, 0, stream>>>(Wq, WqT, 1024, 1024);
    wprep<<<dim3(32, 32),  tb, 0, stream>>>(Wk, WkT, 1024, 1024);
    wprep<<<dim3(32, 32),  tb, 0, stream>>>(Wv, WvT, 1024, 1024);
    wprep<<<dim3(32, 32),  tb, 0, stream>>>(Wo, WoT, 1024, 1024);
    wprep<<<dim3(128, 32), tb, 0, stream>>>(W1, W1T, 1024, 4096);
    wprep<<<dim3(32, 128), tb, 0, stream>>>(W2, W2T, 4096, 1024);

    // LN1 + window partition
    ln_kernel<1><<<M, 256, 0, stream>>>(x, g1, beta1, hw);

    // QKV projections
    gemm128<0><<<dim3(8, 256), 256, 0, stream>>>(hw, WqT, bq, nullptr, qbf, M, 1024, 1024);
    gemm128<0><<<dim3(8, 256), 256, 0, stream>>>(hw, WkT, bk, nullptr, kbf, M, 1024, 1024);
    gemm128<0><<<dim3(8, 256), 256, 0, stream>>>(hw, WvT, bv, nullptr, vbf, M, 1024, 1024);

    // windowed attention (128 windows x 16 heads)
    attn_kernel<<<2048, 256, 0, stream>>>(qbf, kbf, vbf, ao);

    // O projection + bias + residual + window un-partition -> x2 (fp32)
    gemm128<2><<<dim3(8, 256), 256, 0, stream>>>(ao, WoT, bo, x, x2, M, 1024, 1024);

    // LN2
    ln_kernel<0><<<M, 256, 0, stream>>>(x2, g2, beta2, h2);

    // MLP
    gemm128<1><<<dim3(32, 256), 256, 0, stream>>>(h2, W1T, b1m, nullptr, m1, M, 4096, 1024);
    gemm128<3><<<dim3(8, 256), 256, 0, stream>>>(m1, W2T, b2m, x2, (float*)d_out, M, 1024, 4096);
}